// Round 5
// baseline (88.933 us; speedup 1.0000x reference)
//
#include <hip/hip_runtime.h>
#include <math.h>

#define CC    144
#define WW    9225
#define KWW   10
#define FF    64
#define H1N   128
#define CONVN (WW - KWW + 1)   // 9216
#define CFN   (CC * FF)        // 9216
#define CATN  (CFN + CONVN)    // 18432
#define FCB   (CFN / 4)        // 2304 fc blocks (4 waves each, 1 row/wave)
#define NFULL 144              // 144*64 = 9216 full-lane iterations
#define NTAIL 9                // 9225 - 9216

typedef float f32x4 __attribute__((ext_vector_type(4)));

// ---------------------------------------------------------------------------
// Stage 1 v5: blocks [0,FCB): 4 waves, one fc row per wave, barrier-free.
//   Both W and x are read as SCALAR dwords with lane-consecutive addresses:
//   every load instruction = 64 consecutive dwords = 4 cache lines, vs the
//   v3 pattern (aligned dwordx4 of W + 4 unaligned scalar x) which cost ~82
//   line-lookups per KB of W. Goal: remove the L1-transaction bottleneck.
//             blocks [FCB, FCB+36): conv (256 positions/block).
// ---------------------------------------------------------------------------
__global__ __launch_bounds__(256) void k_front_v5(
    const float* __restrict__ x,     // [C, W]
    const float* __restrict__ Wfc,   // [C, F, W]
    const float* __restrict__ bfc,   // [C, F]
    const float* __restrict__ Kc,    // [C, KW]
    const float* __restrict__ bconv, // [1]
    float* __restrict__ concat)      // [CATN]
{
    __shared__ float sm[CC * KWW];   // used by conv blocks only
    const int bid = blockIdx.x;
    const int tid = threadIdx.x;

    if (bid < FCB) {
        const int wave = tid >> 6;
        const int lane = tid & 63;
        const int r    = bid * 4 + wave;          // fc row [0, CFN)
        const int c    = r >> 6;                  // channel (same for 4 waves)
        const float* __restrict__ wr = Wfc + (size_t)r * WW;
        const float* __restrict__ xr = x + (size_t)c * WW;

        const float* __restrict__ wp = wr + lane;
        const float* __restrict__ xp = xr + lane;

        float acc = 0.f;
        #pragma unroll 8
        for (int k = 0; k < NFULL; ++k)
            acc = fmaf(wp[(size_t)k * 64], xp[(size_t)k * 64], acc);
        if (lane < NTAIL)
            acc += wr[NFULL * 64 + lane] * xr[NFULL * 64 + lane];

        // wave-only reduction — no LDS, no __syncthreads
        #pragma unroll
        for (int off = 32; off > 0; off >>= 1)
            acc += __shfl_xor(acc, off, 64);
        if (lane == 0)
            concat[r] = acc + bfc[r];
    } else {
        // ---- conv: position p = (bid-FCB)*256 + tid
        for (int i = tid; i < CC * KWW; i += 256) sm[i] = Kc[i];
        __syncthreads();

        const int p = (bid - FCB) * 256 + tid;    // 36*256 == 9216 exactly
        float acc = bconv[0];
        for (int c = 0; c < CC; ++c) {
            const float* __restrict__ xr = x + (size_t)c * WW + p;
            const float* __restrict__ kr = sm + c * KWW;
            #pragma unroll
            for (int k = 0; k < KWW; ++k)
                acc = fmaf(xr[k], kr[k], acc);
        }
        concat[CFN + p] = acc;
    }
}

// ---------------------------------------------------------------------------
// Stage 2: 256 blocks; block j = (h = j>>1, half = j&1) half-row partial dot.
// ---------------------------------------------------------------------------
__global__ __launch_bounds__(256) void k_layer1_v2(
    const float* __restrict__ W1,     // [H1, CAT]
    const float* __restrict__ concat, // [CAT]
    float* __restrict__ partial)      // [256]
{
    __shared__ float sm[4];
    const int j = blockIdx.x, tid = threadIdx.x;
    const int h = j >> 1, half = j & 1;
    const f32x4* __restrict__ wr =
        (const f32x4*)(W1 + (size_t)h * CATN + half * (CATN / 2));
    const f32x4* __restrict__ cv =
        (const f32x4*)(concat + half * (CATN / 2));

    float acc = 0.f;
    for (int i = tid; i < CATN / 8; i += 256) {   // 9 iters
        const f32x4 a = wr[i];
        const f32x4 q = cv[i];
        acc += a.x * q.x + a.y * q.y + a.z * q.z + a.w * q.w;
    }
    #pragma unroll
    for (int off = 32; off > 0; off >>= 1)
        acc += __shfl_xor(acc, off, 64);
    if ((tid & 63) == 0) sm[tid >> 6] = acc;
    __syncthreads();
    if (tid == 0)
        partial[j] = sm[0] + sm[1] + sm[2] + sm[3];
}

// ---------------------------------------------------------------------------
// Stage 3: combine partials + bias + relu, dot with W2, relu, sigmoid.
// ---------------------------------------------------------------------------
__global__ __launch_bounds__(128) void k_final_v2(
    const float* __restrict__ partial, // [256]
    const float* __restrict__ b1,      // [H1]
    const float* __restrict__ W2,      // [1, H1]
    const float* __restrict__ b2,      // [1]
    float* __restrict__ out)           // [1]
{
    __shared__ float sm[2];
    const int tid = threadIdx.x;
    float v = fmaxf(partial[2 * tid] + partial[2 * tid + 1] + b1[tid], 0.f)
              * W2[tid];
    #pragma unroll
    for (int off = 32; off > 0; off >>= 1)
        v += __shfl_xor(v, off, 64);
    if ((tid & 63) == 0) sm[tid >> 6] = v;
    __syncthreads();
    if (tid == 0) {
        float z = sm[0] + sm[1] + b2[0];
        z = fmaxf(z, 0.f);
        out[0] = 1.f / (1.f + expf(-z));
    }
}

extern "C" void kernel_launch(void* const* d_in, const int* in_sizes, int n_in,
                              void* d_out, int out_size, void* d_ws, size_t ws_size,
                              hipStream_t stream) {
    const float* x     = (const float*)d_in[0];
    const float* Wfc   = (const float*)d_in[1];
    const float* bfc   = (const float*)d_in[2];
    const float* Kc    = (const float*)d_in[3];
    const float* bconv = (const float*)d_in[4];
    const float* W1    = (const float*)d_in[5];
    const float* b1    = (const float*)d_in[6];
    const float* W2    = (const float*)d_in[7];
    const float* b2    = (const float*)d_in[8];
    float* out = (float*)d_out;

    float* concat  = (float*)d_ws;         // [CATN]
    float* partial = concat + CATN;        // [256]

    k_front_v5 <<<FCB + (CONVN / 256), 256, 0, stream>>>(
        x, Wfc, bfc, Kc, bconv, concat);
    k_layer1_v2<<<256, 256, 0, stream>>>(W1, concat, partial);
    k_final_v2 <<<1, 128, 0, stream>>>(partial, b1, W2, b2, out);
}

// Round 6
// 88.844 us; speedup vs baseline: 1.0010x; 1.0010x over previous
//
#include <hip/hip_runtime.h>
#include <math.h>

#define CC    144
#define WW    9225
#define KWW   10
#define FF    64
#define H1N   128
#define CONVN (WW - KWW + 1)   // 9216
#define CFN   (CC * FF)        // 9216
#define CATN  (CFN + CONVN)    // 18432
#define FCB2  (CC * 8)         // 1152 fc blocks: (channel c, f-group g of 8)
#define NFULL 144              // 144*64 = 9216 full-lane iterations
#define NTAIL 9                // 9225 - 9216

typedef float f32x4 __attribute__((ext_vector_type(4)));

// ---------------------------------------------------------------------------
// Stage 1 v6: fc blocks stage the channel's x row in LDS once, then each wave
// streams TWO full contiguous Wfc rows (scalar lane-consecutive global loads)
// against conflict-free lane-consecutive ds_read_b32. No x global stream.
//   blocks [0, FCB2): fc.  blocks [FCB2, FCB2+36): conv (256 positions each).
// ---------------------------------------------------------------------------
__global__ __launch_bounds__(256) void k_front_v6(
    const float* __restrict__ x,     // [C, W]
    const float* __restrict__ Wfc,   // [C, F, W]
    const float* __restrict__ bfc,   // [C, F]
    const float* __restrict__ Kc,    // [C, KW]
    const float* __restrict__ bconv, // [1]
    float* __restrict__ concat)      // [CATN]
{
    __shared__ float smem[WW];       // 36.9 KB; conv blocks use first 1440
    const int bid = blockIdx.x;
    const int tid = threadIdx.x;

    if (bid < FCB2) {
        const int c = bid >> 3;                   // channel
        const int g = bid & 7;                    // f-group
        const float* __restrict__ xr = x + (size_t)c * WW;

        // ---- stage x row into LDS (lane-consecutive scalar, coalesced)
        for (int i = tid; i < WW; i += 256) smem[i] = xr[i];
        __syncthreads();

        // ---- each wave: rows r0, r0+1 (two contiguous 36.9 KB W streams)
        const int wave = tid >> 6;
        const int lane = tid & 63;
        const int f0   = g * 8 + wave * 2;        // covers all 64 f per c
        const int r0   = (c << 6) + f0;
        const float* __restrict__ w0 = Wfc + (size_t)r0 * WW + lane;
        const float* __restrict__ w1 = w0 + WW;

        float a0 = 0.f, a1 = 0.f;
        #pragma unroll 8
        for (int k = 0; k < NFULL; ++k) {
            const int idx = (k << 6);
            const float xv = smem[idx + lane];
            a0 = fmaf(w0[idx], xv, a0);
            a1 = fmaf(w1[idx], xv, a1);
        }
        if (lane < NTAIL) {
            const int idx = NFULL * 64 + lane;
            const float xv = smem[idx];
            a0 = fmaf(w0[idx - lane + lane], xv, a0);   // w0 already +lane
            a1 = fmaf(w1[idx - lane + lane], xv, a1);
        }
        // note: w0/w1 are base+lane, and idx above includes +lane only via
        // smem; for the tail the element index is NFULL*64+lane, matching
        // w0[NFULL*64] since w0 = base+lane. (w0[idx-lane+lane] == w0[idx]
        // with idx = NFULL*64 would double-count lane; keep explicit form.)

        // wave-only reduction — no LDS, no __syncthreads
        #pragma unroll
        for (int off = 32; off > 0; off >>= 1) {
            a0 += __shfl_xor(a0, off, 64);
            a1 += __shfl_xor(a1, off, 64);
        }
        if (lane == 0) {
            concat[r0]     = a0 + bfc[r0];
            concat[r0 + 1] = a1 + bfc[r0 + 1];
        }
    } else {
        // ---- conv: position p = (bid-FCB2)*256 + tid
        for (int i = tid; i < CC * KWW; i += 256) smem[i] = Kc[i];
        __syncthreads();

        const int p = (bid - FCB2) * 256 + tid;   // 36*256 == 9216 exactly
        float acc = bconv[0];
        for (int c = 0; c < CC; ++c) {
            const float* __restrict__ xr = x + (size_t)c * WW + p;
            const float* __restrict__ kr = smem + c * KWW;
            #pragma unroll
            for (int k = 0; k < KWW; ++k)
                acc = fmaf(xr[k], kr[k], acc);
        }
        concat[CFN + p] = acc;
    }
}

// ---------------------------------------------------------------------------
// Stage 2: 256 blocks; block j = (h = j>>1, half = j&1) half-row partial dot.
// ---------------------------------------------------------------------------
__global__ __launch_bounds__(256) void k_layer1_v2(
    const float* __restrict__ W1,     // [H1, CAT]
    const float* __restrict__ concat, // [CAT]
    float* __restrict__ partial)      // [256]
{
    __shared__ float sm[4];
    const int j = blockIdx.x, tid = threadIdx.x;
    const int h = j >> 1, half = j & 1;
    const f32x4* __restrict__ wr =
        (const f32x4*)(W1 + (size_t)h * CATN + half * (CATN / 2));
    const f32x4* __restrict__ cv =
        (const f32x4*)(concat + half * (CATN / 2));

    float acc = 0.f;
    for (int i = tid; i < CATN / 8; i += 256) {   // 9 iters
        const f32x4 a = wr[i];
        const f32x4 q = cv[i];
        acc += a.x * q.x + a.y * q.y + a.z * q.z + a.w * q.w;
    }
    #pragma unroll
    for (int off = 32; off > 0; off >>= 1)
        acc += __shfl_xor(acc, off, 64);
    if ((tid & 63) == 0) sm[tid >> 6] = acc;
    __syncthreads();
    if (tid == 0)
        partial[j] = sm[0] + sm[1] + sm[2] + sm[3];
}

// ---------------------------------------------------------------------------
// Stage 3: combine partials + bias + relu, dot with W2, relu, sigmoid.
// ---------------------------------------------------------------------------
__global__ __launch_bounds__(128) void k_final_v2(
    const float* __restrict__ partial, // [256]
    const float* __restrict__ b1,      // [H1]
    const float* __restrict__ W2,      // [1, H1]
    const float* __restrict__ b2,      // [1]
    float* __restrict__ out)           // [1]
{
    __shared__ float sm[2];
    const int tid = threadIdx.x;
    float v = fmaxf(partial[2 * tid] + partial[2 * tid + 1] + b1[tid], 0.f)
              * W2[tid];
    #pragma unroll
    for (int off = 32; off > 0; off >>= 1)
        v += __shfl_xor(v, off, 64);
    if ((tid & 63) == 0) sm[tid >> 6] = v;
    __syncthreads();
    if (tid == 0) {
        float z = sm[0] + sm[1] + b2[0];
        z = fmaxf(z, 0.f);
        out[0] = 1.f / (1.f + expf(-z));
    }
}

extern "C" void kernel_launch(void* const* d_in, const int* in_sizes, int n_in,
                              void* d_out, int out_size, void* d_ws, size_t ws_size,
                              hipStream_t stream) {
    const float* x     = (const float*)d_in[0];
    const float* Wfc   = (const float*)d_in[1];
    const float* bfc   = (const float*)d_in[2];
    const float* Kc    = (const float*)d_in[3];
    const float* bconv = (const float*)d_in[4];
    const float* W1    = (const float*)d_in[5];
    const float* b1    = (const float*)d_in[6];
    const float* W2    = (const float*)d_in[7];
    const float* b2    = (const float*)d_in[8];
    float* out = (float*)d_out;

    float* concat  = (float*)d_ws;         // [CATN]
    float* partial = concat + CATN;        // [256]

    k_front_v6 <<<FCB2 + (CONVN / 256), 256, 0, stream>>>(
        x, Wfc, bfc, Kc, bconv, concat);
    k_layer1_v2<<<256, 256, 0, stream>>>(W1, concat, partial);
    k_final_v2 <<<1, 128, 0, stream>>>(partial, b1, W2, b2, out);
}